// Round 6
// baseline (170.523 us; speedup 1.0000x reference)
//
#include <hip/hip_runtime.h>

#define H 256
#define W 256
#define W4 (W / 4)            // 64 float4 per image row
#define OWID 250
#define NIMG 256              // B*D
#define BAND 10               // output rows per wave; 25*10 = 250 exactly
#define NBANDS 25
#define NBLK (NBANDS * NIMG)  // 6400 partials
#define RIN 16                // input rows per band: BAND + 6, uniform for ALL bands
#define WPB 4                 // waves per block
#define NBLOCKS (NBLK / WPB)  // 1600 blocks of 256 threads

__device__ __forceinline__ float4 f4zero() { return make_float4(0.f, 0.f, 0.f, 0.f); }

// NOTE (measured, rounds 3+4): adding a min-waves/EU arg to __launch_bounds__
// makes the allocator spill the float4 pipelines to scratch (WRITE_SIZE
// 0.2 MB -> 85-114 MB). Keep plain __launch_bounds__(256).
//
// NOTE (round 6 theory): rounds 2-5 fully unrolled 16 rows = ~25+ KB of
// straight-line code, streamed once per wave -> I$ (32 KB/CU) streaming
// stalls (VALUBusy pinned ~29% with no data-side excuse). This version
// RE-ROLLS the row loop into small 2-row bodies (named regs, no arrays ->
// no scratch; #pragma unroll 1) so the hot code is ~6 KB and I$-resident.
__global__ __launch_bounds__(256) void ssim_band_kernel(
    const float* __restrict__ X, const float* __restrict__ Y,
    float* __restrict__ partial)
{
    const int lane = threadIdx.x & 63;          // 0..63, owns cols 4*lane..+3
    const int wid  = blockIdx.x * WPB + (threadIdx.x >> 6);  // 0..6399
    const int img  = wid / NBANDS;              // 0..255
    const int band = wid % NBANDS;              // 0..24
    const int r0 = band * BAND;

    const float4* Xp = (const float4*)X + ((size_t)img * H + r0) * W4 + lane;
    const float4* Yp = (const float4*)Y + ((size_t)img * H + r0) * W4 + lane;

    // 4 vertical moments: sx, sy, sxy, spp = Σ(x²+y²).
    float4 sx = f4zero(), sy = f4zero(), sxy = f4zero(), spp = f4zero();

    // SSIM constants with 1/49 (=a) and 49/48 (=covn) folded in.
    const float C1  = 1e-4f;            // (0.01)^2
    const float C2  = 9e-4f;            // (0.03)^2
    const float AA  = 1.f / 2401.f;     // a^2
    const float C2A = 2.f / 2401.f;     // 2 a^2
    const float T1  = 1.f / 24.f;       // 2 covn a
    const float T2  = -1.f / 1176.f;    // -2 covn a^2
    const float T3  = 1.f / 48.f;       // covn a
    const float T4  = -1.f / 2352.f;    // -covn a^2
    float lsum = 0.0f;

    // Accumulate row (xn,yn) into the vertical sums.
    #define VADD(xn, yn)                                                     \
    {                                                                        \
        sx.x += xn.x; sx.y += xn.y; sx.z += xn.z; sx.w += xn.w;              \
        sy.x += yn.x; sy.y += yn.y; sy.z += yn.z; sy.w += yn.w;              \
        sxy.x = fmaf(xn.x, yn.x, sxy.x); sxy.y = fmaf(xn.y, yn.y, sxy.y);    \
        sxy.z = fmaf(xn.z, yn.z, sxy.z); sxy.w = fmaf(xn.w, yn.w, sxy.w);    \
        spp.x = fmaf(xn.x, xn.x, fmaf(yn.x, yn.x, spp.x));                   \
        spp.y = fmaf(xn.y, xn.y, fmaf(yn.y, yn.y, spp.y));                   \
        spp.z = fmaf(xn.z, xn.z, fmaf(yn.z, yn.z, spp.z));                   \
        spp.w = fmaf(xn.w, xn.w, fmaf(yn.w, yn.w, spp.w));                   \
    }
    // Slide: + entering (xn,yn), - leaving (xo,yo).
    #define VSLIDE(xn, yn, xo, yo)                                           \
    {                                                                        \
        sx.x += xn.x - xo.x; sx.y += xn.y - xo.y;                            \
        sx.z += xn.z - xo.z; sx.w += xn.w - xo.w;                            \
        sy.x += yn.x - yo.x; sy.y += yn.y - yo.y;                            \
        sy.z += yn.z - yo.z; sy.w += yn.w - yo.w;                            \
        sxy.x = fmaf(xn.x, yn.x, fmaf(-xo.x, yo.x, sxy.x));                  \
        sxy.y = fmaf(xn.y, yn.y, fmaf(-xo.y, yo.y, sxy.y));                  \
        sxy.z = fmaf(xn.z, yn.z, fmaf(-xo.z, yo.z, sxy.z));                  \
        sxy.w = fmaf(xn.w, yn.w, fmaf(-xo.w, yo.w, sxy.w));                  \
        spp.x = fmaf(xn.x, xn.x, fmaf(yn.x, yn.x, fmaf(-xo.x, xo.x, fmaf(-yo.x, yo.x, spp.x)))); \
        spp.y = fmaf(xn.y, xn.y, fmaf(yn.y, yn.y, fmaf(-xo.y, xo.y, fmaf(-yo.y, yo.y, spp.y)))); \
        spp.z = fmaf(xn.z, xn.z, fmaf(yn.z, yn.z, fmaf(-xo.z, xo.z, fmaf(-yo.z, yo.z, spp.z)))); \
        spp.w = fmaf(xn.w, xn.w, fmaf(yn.w, yn.w, fmaf(-xo.w, xo.w, fmaf(-yo.w, yo.w, spp.w)))); \
    }
    // Horizontal 7-tap via cross-lane shuffles. OOB shuffles at lanes 62/63
    // feed only columns masked by the OWID test.
    #define HWIN(S, WA)                                                      \
    {                                                                        \
        const float bx = __shfl_down(S.x, 1);                                \
        const float by = __shfl_down(S.y, 1);                                \
        const float bz = __shfl_down(S.z, 1);                                \
        const float bw = __shfl_down(S.w, 1);                                \
        const float cx = __shfl_down(S.x, 2);                                \
        const float cy = __shfl_down(S.y, 2);                                \
        WA[0] = S.x + S.y + S.z + S.w + bx + by + bz;                        \
        WA[1] = WA[0] - S.x + bw;                                            \
        WA[2] = WA[1] - S.y + cx;                                            \
        WA[3] = WA[2] - S.z + cy;                                            \
    }
    // One output row: 4 horizontal windows + SSIM + masked accumulate.
    #define OUTROW()                                                         \
    {                                                                        \
        float wx[4], wy[4], wpp[4], wxy[4];                                  \
        HWIN(sx,  wx)                                                        \
        HWIN(sy,  wy)                                                        \
        HWIN(spp, wpp)                                                       \
        HWIN(sxy, wxy)                                                       \
        _Pragma("unroll")                                                    \
        for (int s = 0; s < 4; ++s) {                                        \
            const float P  = wx[s] * wy[s];                                  \
            const float Qs = fmaf(wy[s], wy[s], wx[s] * wx[s]);              \
            const float A1 = fmaf(C2A, P, C1);                               \
            const float B1 = fmaf(AA, Qs, C1);                               \
            const float A2 = fmaf(T1, wxy[s], fmaf(T2, P, C2));              \
            const float B2 = fmaf(T3, wpp[s], fmaf(T4, Qs, C2));             \
            const float S  = (A1 * A2) * __builtin_amdgcn_rcpf(B1 * B2);     \
            if (4 * lane + s < OWID) lsum += S;                              \
        }                                                                    \
    }

    // Depth-2 new-row pipeline: A = even rows, B = odd rows (named regs).
    float4 pxA = Xp[0],  pyA = Yp[0];
    float4 pxB = Xp[W4], pyB = Yp[W4];

    // ---- Prologue rows 0..5 (rolled, 3 x 2-row body) ----
    #pragma unroll 1
    for (int q = 0; q < 6; q += 2) {
        const float4 xnA = pxA, ynA = pyA;
        pxA = Xp[(q + 2) * W4]; pyA = Yp[(q + 2) * W4];   // loads rows 2,4,6
        VADD(xnA, ynA)
        const float4 xnB = pxB, ynB = pyB;
        pxB = Xp[(q + 3) * W4]; pyB = Yp[(q + 3) * W4];   // loads rows 3,5,7
        VADD(xnB, ynB)
    }
    // Reload row 0 (L2-resident) for row 7's subtract.
    const float4 ox0 = Xp[0], oy0 = Yp[0];

    // ---- Rows 6,7 (first two outputs; row 6 subtracts nothing) ----
    {
        const float4 xn = pxA, yn = pyA;          // row 6
        pxA = Xp[8 * W4]; pyA = Yp[8 * W4];
        VADD(xn, yn)
        OUTROW()
    }
    // Leaving-row pipeline for pair (8,9): rows 1,2 (L2-resident reloads).
    float4 oxA = Xp[1 * W4], oyA = Yp[1 * W4];
    float4 oxB = Xp[2 * W4], oyB = Yp[2 * W4];
    {
        const float4 xn = pxB, yn = pyB;          // row 7
        pxB = Xp[9 * W4]; pyB = Yp[9 * W4];
        VSLIDE(xn, yn, ox0, oy0)
        OUTROW()
    }

    // ---- Main rolled loop: pairs (8,9)(10,11)(12,13)(14,15) ----
    #pragma unroll 1
    for (int q = 8; q <= 14; q += 2) {
        // row q: enter pxA (row q), leave oxA (row q-7)
        const float4 xnA = pxA, ynA = pyA;
        const int nA = (q + 2 <= 15) ? (q + 2) : 15;      // clamp: harmless reload
        pxA = Xp[nA * W4]; pyA = Yp[nA * W4];
        const float4 xoA = oxA, yoA = oyA;
        oxA = Xp[(q - 5) * W4]; oyA = Yp[(q - 5) * W4];   // next pair leaves q-5
        VSLIDE(xnA, ynA, xoA, yoA)
        OUTROW()

        // row q+1: enter pxB (row q+1), leave oxB (row q-6)
        const float4 xnB = pxB, ynB = pyB;
        const int nB = (q + 3 <= 15) ? (q + 3) : 15;
        pxB = Xp[nB * W4]; pyB = Yp[nB * W4];
        const float4 xoB = oxB, yoB = oyB;
        oxB = Xp[(q - 4) * W4]; oyB = Yp[(q - 4) * W4];   // next pair leaves q-4
        VSLIDE(xnB, ynB, xoB, yoB)
        OUTROW()
    }

    #undef VADD
    #undef VSLIDE
    #undef HWIN
    #undef OUTROW

    // Wave reduction -> one partial per wave.
    #pragma unroll
    for (int off = 32; off > 0; off >>= 1)
        lsum += __shfl_down(lsum, off, 64);
    if (lane == 0) partial[wid] = lsum;   // wid == img*NBANDS + band
}

__global__ __launch_bounds__(256) void ssim_reduce_kernel(
    const float* __restrict__ partial, float* __restrict__ out)
{
    const int tid = threadIdx.x;
    double acc = 0.0;
    for (int i = tid; i < NBLK; i += 256)
        acc += (double)partial[i];
    #pragma unroll
    for (int off = 32; off > 0; off >>= 1)
        acc += __shfl_down(acc, off, 64);
    __shared__ double wsumd[4];
    if ((tid & 63) == 0) wsumd[tid >> 6] = acc;
    __syncthreads();
    if (tid == 0) {
        double total = wsumd[0] + wsumd[1] + wsumd[2] + wsumd[3];
        float loss = (float)(1.0 - total / 16000000.0);
        out[0] = loss; out[1] = loss; out[2] = loss; out[3] = loss;
    }
}

extern "C" void kernel_launch(void* const* d_in, const int* in_sizes, int n_in,
                              void* d_out, int out_size, void* d_ws, size_t ws_size,
                              hipStream_t stream) {
    const float* X = (const float*)d_in[0];
    const float* Y = (const float*)d_in[1];
    // d_in[2] is the uniform 7x7 filter (1/49 everywhere) — constant-folded.
    float* out = (float*)d_out;
    float* partial = (float*)d_ws;   // 6400 floats = 25.6 KB

    hipLaunchKernelGGL(ssim_band_kernel, dim3(NBLOCKS), dim3(256), 0, stream,
                       X, Y, partial);
    hipLaunchKernelGGL(ssim_reduce_kernel, dim3(1), dim3(256), 0, stream,
                       partial, out);
}

// Round 7
// 166.322 us; speedup vs baseline: 1.0253x; 1.0253x over previous
//
#include <hip/hip_runtime.h>

#define H 256
#define W 256
#define W4 (W / 4)            // 64 float4 per image row
#define OWID 250
#define NIMG 256              // B*D
#define BAND 10               // output rows per stream; 25*10 = 250 exactly
#define NBANDS 25
#define NPAIR 3200            // waves; each handles TWO (img,band) units
#define WPB 4                 // waves per block
#define NBLOCKS (NPAIR / WPB) // 800 blocks of 256 threads
#define RIN 16                // input rows per band: BAND + 6

// Measured landmines (do not regress):
//  - rounds 3+4: ANY min-waves arg on __launch_bounds__ makes the allocator
//    spill the float4 pipelines (WRITE_SIZE 0.2MB -> 85-114MB). Plain (256).
//  - round 6: re-rolling the row loop regressed (51 -> 60us, FETCH +45%).
//    Keep the full static unroll.
//  - round 6: L3-resident dispatches (hbm ~0) run the SAME time as HBM ones
//    -> kernel is exposed-latency-bound, not BW-bound. This round adds
//    per-wave ILP (two independent band-streams per wave) to fill the stall.

__device__ __forceinline__ float4 f4zero() { return make_float4(0.f, 0.f, 0.f, 0.f); }

// SSIM constants with 1/49 (=a) and 49/48 (=covn) folded in.
#define CC1 1e-4f             // (0.01)^2
#define CC2 9e-4f             // (0.03)^2
#define KAA (1.f / 2401.f)    // a^2
#define K2A (2.f / 2401.f)    // 2 a^2
#define KT1 (1.f / 24.f)      // 2 covn a
#define KT2 (-1.f / 1176.f)   // -2 covn a^2
#define KT3 (1.f / 48.f)      // covn a
#define KT4 (-1.f / 2352.f)   // -covn a^2

struct Stream {
    const float4* Xp;
    const float4* Yp;
    float4 sx, sy, sxy, spp;      // vertical moments (spp = sum x^2+y^2)
    float4 px0, py0, px1, py1;    // entering-row pipeline (parity slots)
    float4 ox0, oy0, ox1, oy1;    // leaving-row pipeline (L1/L2 reloads)
};

__device__ __forceinline__ void s_init(Stream& s, const float* X, const float* Y,
                                       int img, int band, int lane) {
    const int r0 = band * BAND;
    s.Xp = (const float4*)X + ((size_t)img * H + r0) * W4 + lane;
    s.Yp = (const float4*)Y + ((size_t)img * H + r0) * W4 + lane;
    s.sx = f4zero(); s.sy = f4zero(); s.sxy = f4zero(); s.spp = f4zero();
    s.px0 = s.Xp[0];  s.py0 = s.Yp[0];
    s.px1 = s.Xp[W4]; s.py1 = s.Yp[W4];
}

// One row of one stream: vertical slide + (for output rows) horizontal 7-tap
// via cross-lane shuffles + SSIM accumulate. All compile-time indexed.
template<int R>
__device__ __forceinline__ void s_row(Stream& s, const float4 xn, const float4 yn,
                                      const float4 xo, const float4 yo,
                                      const int lane, float& lsum) {
    // Vertical slide (+ entering, - leaving; leaving is zeros for R <= 6).
    s.sx.x += xn.x - xo.x; s.sx.y += xn.y - xo.y;
    s.sx.z += xn.z - xo.z; s.sx.w += xn.w - xo.w;
    s.sy.x += yn.x - yo.x; s.sy.y += yn.y - yo.y;
    s.sy.z += yn.z - yo.z; s.sy.w += yn.w - yo.w;
    s.sxy.x = fmaf(xn.x, yn.x, fmaf(-xo.x, yo.x, s.sxy.x));
    s.sxy.y = fmaf(xn.y, yn.y, fmaf(-xo.y, yo.y, s.sxy.y));
    s.sxy.z = fmaf(xn.z, yn.z, fmaf(-xo.z, yo.z, s.sxy.z));
    s.sxy.w = fmaf(xn.w, yn.w, fmaf(-xo.w, yo.w, s.sxy.w));
    s.spp.x = fmaf(xn.x, xn.x, fmaf(yn.x, yn.x, fmaf(-xo.x, xo.x, fmaf(-yo.x, yo.x, s.spp.x))));
    s.spp.y = fmaf(xn.y, xn.y, fmaf(yn.y, yn.y, fmaf(-xo.y, xo.y, fmaf(-yo.y, yo.y, s.spp.y))));
    s.spp.z = fmaf(xn.z, xn.z, fmaf(yn.z, yn.z, fmaf(-xo.z, xo.z, fmaf(-yo.z, yo.z, s.spp.z))));
    s.spp.w = fmaf(xn.w, xn.w, fmaf(yn.w, yn.w, fmaf(-xo.w, xo.w, fmaf(-yo.w, yo.w, s.spp.w))));

    if constexpr (R >= 6) {
        // Horizontal 7-tap: lane L col s window = cols 4L+s..4L+s+6; needs
        // lane L+1's 4 sums and lane L+2's first 2. OOB shuffles at lanes
        // 62/63 feed only columns masked by the OWID test.
        float wx[4], wy[4], wpp[4], wxy[4];
        #define HWIN(S, WA)                                                  \
        {                                                                    \
            const float bx = __shfl_down(S.x, 1);                            \
            const float by = __shfl_down(S.y, 1);                            \
            const float bz = __shfl_down(S.z, 1);                            \
            const float bw = __shfl_down(S.w, 1);                            \
            const float cx = __shfl_down(S.x, 2);                            \
            const float cy = __shfl_down(S.y, 2);                            \
            WA[0] = S.x + S.y + S.z + S.w + bx + by + bz;                    \
            WA[1] = WA[0] - S.x + bw;                                        \
            WA[2] = WA[1] - S.y + cx;                                        \
            WA[3] = WA[2] - S.z + cy;                                        \
        }
        HWIN(s.sx,  wx)
        HWIN(s.sy,  wy)
        HWIN(s.spp, wpp)
        HWIN(s.sxy, wxy)
        #undef HWIN
        #pragma unroll
        for (int c = 0; c < 4; ++c) {
            const float P  = wx[c] * wy[c];
            const float Qs = fmaf(wy[c], wy[c], wx[c] * wx[c]);
            const float A1 = fmaf(K2A, P, CC1);
            const float B1 = fmaf(KAA, Qs, CC1);
            const float A2 = fmaf(KT1, wxy[c], fmaf(KT2, P, CC2));
            const float B2 = fmaf(KT3, wpp[c], fmaf(KT4, Qs, CC2));
            const float S  = (A1 * A2) * __builtin_amdgcn_rcpf(B1 * B2);
            if (4 * lane + c < OWID) lsum += S;   // mask cols >= 250
        }
    }
}

// One iteration: capture both streams' pipelined rows, issue both streams'
// refills (8 loads -> in flight across the whole compute), then compute both
// rows. 2x independent work per latency event vs round 5.
template<int R>
__device__ __forceinline__ void stepPair(Stream& a, Stream& b,
                                         const int lane, float& lsum) {
    const float4 xnA = (R & 1) ? a.px1 : a.px0;
    const float4 ynA = (R & 1) ? a.py1 : a.py0;
    const float4 xnB = (R & 1) ? b.px1 : b.px0;
    const float4 ynB = (R & 1) ? b.py1 : b.py0;
    float4 xoA = f4zero(), yoA = f4zero(), xoB = f4zero(), yoB = f4zero();
    if constexpr (R >= 7) {
        xoA = (R & 1) ? a.ox1 : a.ox0;  yoA = (R & 1) ? a.oy1 : a.oy0;
        xoB = (R & 1) ? b.ox1 : b.ox0;  yoB = (R & 1) ? b.oy1 : b.oy0;
    }
    // Refill entering-row slots with row R+2 (depth-2 pipeline).
    if constexpr (R + 2 < RIN) {
        if constexpr (R & 1) {
            a.px1 = a.Xp[(R + 2) * W4]; a.py1 = a.Yp[(R + 2) * W4];
            b.px1 = b.Xp[(R + 2) * W4]; b.py1 = b.Yp[(R + 2) * W4];
        } else {
            a.px0 = a.Xp[(R + 2) * W4]; a.py0 = a.Yp[(R + 2) * W4];
            b.px0 = b.Xp[(R + 2) * W4]; b.py0 = b.Yp[(R + 2) * W4];
        }
    }
    // Issue leaving-row (R-5) for use at R+2; L1/L2-resident reload.
    if constexpr (R >= 5 && R + 2 <= RIN - 1) {
        if constexpr (R & 1) {
            a.ox1 = a.Xp[(R - 5) * W4]; a.oy1 = a.Yp[(R - 5) * W4];
            b.ox1 = b.Xp[(R - 5) * W4]; b.oy1 = b.Yp[(R - 5) * W4];
        } else {
            a.ox0 = a.Xp[(R - 5) * W4]; a.oy0 = a.Yp[(R - 5) * W4];
            b.ox0 = b.Xp[(R - 5) * W4]; b.oy0 = b.Yp[(R - 5) * W4];
        }
    }
    s_row<R>(a, xnA, ynA, xoA, yoA, lane, lsum);
    s_row<R>(b, xnB, ynB, xoB, yoB, lane, lsum);
    if constexpr (R + 1 < RIN) stepPair<R + 1>(a, b, lane, lsum);
}

__global__ __launch_bounds__(256) void ssim_band_kernel(
    const float* __restrict__ X, const float* __restrict__ Y,
    float* __restrict__ partial)
{
    const int lane = threadIdx.x & 63;
    const int w    = blockIdx.x * WPB + (threadIdx.x >> 6);   // 0..3199
    // Stream A: images 0..127; stream B: images 128..255 (same band index).
    const int imgA  = w / NBANDS;          // 0..127
    const int band  = w % NBANDS;          // 0..24
    const int imgB  = imgA + 128;

    Stream a, b;
    s_init(a, X, Y, imgA, band, lane);
    s_init(b, X, Y, imgB, band, lane);

    float lsum = 0.0f;
    stepPair<0>(a, b, lane, lsum);

    // Wave reduction -> one partial per wave (covers both streams).
    #pragma unroll
    for (int off = 32; off > 0; off >>= 1)
        lsum += __shfl_down(lsum, off, 64);
    if (lane == 0) partial[w] = lsum;
}

__global__ __launch_bounds__(256) void ssim_reduce_kernel(
    const float* __restrict__ partial, float* __restrict__ out)
{
    const int tid = threadIdx.x;
    double acc = 0.0;
    for (int i = tid; i < NPAIR; i += 256)
        acc += (double)partial[i];
    #pragma unroll
    for (int off = 32; off > 0; off >>= 1)
        acc += __shfl_down(acc, off, 64);
    __shared__ double wsumd[4];
    if ((tid & 63) == 0) wsumd[tid >> 6] = acc;
    __syncthreads();
    if (tid == 0) {
        double total = wsumd[0] + wsumd[1] + wsumd[2] + wsumd[3];
        float loss = (float)(1.0 - total / 16000000.0);
        out[0] = loss; out[1] = loss; out[2] = loss; out[3] = loss;
    }
}

extern "C" void kernel_launch(void* const* d_in, const int* in_sizes, int n_in,
                              void* d_out, int out_size, void* d_ws, size_t ws_size,
                              hipStream_t stream) {
    const float* X = (const float*)d_in[0];
    const float* Y = (const float*)d_in[1];
    // d_in[2] is the uniform 7x7 filter (1/49 everywhere) — constant-folded.
    float* out = (float*)d_out;
    float* partial = (float*)d_ws;   // 3200 floats = 12.8 KB

    hipLaunchKernelGGL(ssim_band_kernel, dim3(NBLOCKS), dim3(256), 0, stream,
                       X, Y, partial);
    hipLaunchKernelGGL(ssim_reduce_kernel, dim3(1), dim3(256), 0, stream,
                       partial, out);
}

// Round 8
// 158.773 us; speedup vs baseline: 1.0740x; 1.0475x over previous
//
#include <hip/hip_runtime.h>

#define H 256
#define W 256
#define W4 (W / 4)            // 64 float4 per image row
#define OWID 250
#define NIMG 256              // B*D
#define BAND 10               // output rows per wave; 25*10 = 250 exactly
#define NBANDS 25
#define NBLK (NBANDS * NIMG)  // 6400 partials
#define RIN 16                // input rows per band: BAND + 6
#define WPB 4                 // waves per block
#define NBLOCKS (NBLK / WPB)  // 1600 blocks of 256 threads

// Measured landmines (do not regress):
//  - R3/R4: ANY min-waves arg on __launch_bounds__ -> allocator spills the
//    float4 pipelines (WRITE_SIZE 0.2MB -> 85-114MB). Plain (256) only.
//  - R6: re-rolling the row loop regressed (51->60us). Keep full static unroll.
//  - R6: L3-resident dispatches run the SAME time as HBM ones -> latency-
//    bound, not BW-bound.
//  - R7: dual-stream ILP cut per-row cost 2.9K->1.8K cycles but VGPR 112
//    crossed the 64-VGPR tier (waves/SIMD halve at 64) and residency loss
//    canceled it. ALL state must fit <=64 VGPR.
//  - This round: tier-matched prefetch depths. Enter rows (HBM/L3, ~900cy)
//    get depth-3; leave rows (L2 re-reads, ~250cy) get depth-1. Same total
//    registers as R5's 2/2 split, better coverage on the long pole.

__device__ __forceinline__ float4 f4zero() { return make_float4(0.f, 0.f, 0.f, 0.f); }

// SSIM constants with 1/49 (=a) and 49/48 (=covn) folded in.
#define CC1 1e-4f             // (0.01)^2
#define CC2 9e-4f             // (0.03)^2
#define KAA (1.f / 2401.f)    // a^2
#define K2A (2.f / 2401.f)    // 2 a^2
#define KT1 (1.f / 24.f)      // 2 covn a
#define KT2 (-1.f / 1176.f)   // -2 covn a^2
#define KT3 (1.f / 48.f)      // covn a
#define KT4 (-1.f / 2352.f)   // -covn a^2

struct Ctx {
    const float4* Xp;
    const float4* Yp;
    float4 sx, sy, sxy, spp;        // vertical moments (spp = sum x^2+y^2)
    float4 ex[3], ey[3];            // entering-row pipeline, depth 3 (HBM/L3)
    float4 lx, ly;                  // leaving-row pipeline, depth 1 (L2 re-read)
};

// Horizontal 7-tap via prefix decomposition: 4 shuffles/moment (was 6) and
// four independent 2-add chains (was one serial 4-chain).
//   own: p1=S.x, p2=p1+S.y, p3=p2+S.z, E=p3+S.w
//   w0 = E + p3'        (': lane+1)
//   w1 = (E - p1) + E'
//   w2 = (E - p2) + E' + p1''   ('': lane+2)
//   w3 = (E - p3) + E' + p2''
// OOB shuffles at lanes 62/63 feed only columns killed by the masks.
__device__ __forceinline__ void hwin4(const float4 S, float w[4]) {
    const float p1 = S.x;
    const float p2 = p1 + S.y;
    const float p3 = p2 + S.z;
    const float E  = p3 + S.w;
    const float n3 = __shfl_down(p3, 1);
    const float nE = __shfl_down(E, 1);
    const float f1 = __shfl_down(p1, 2);
    const float f2 = __shfl_down(p2, 2);
    w[0] = E + n3;
    w[1] = (E - p1) + nE;
    w[2] = (E - p2) + nE + f1;
    w[3] = (E - p3) + nE + f2;
}

template<int R>
__device__ __forceinline__ void step(Ctx& c, const float m01, const float m23,
                                     float& lsum) {
    // Capture pipelined rows for this iteration.
    const float4 xn = c.ex[R % 3], yn = c.ey[R % 3];     // row R (issued R-3)
    float4 xo = f4zero(), yo = f4zero();
    if constexpr (R >= 7) { xo = c.lx; yo = c.ly; }      // row R-7 (issued R-1)

    // Refill: enter row R+3 (depth-3; covers ~1400cy >= HBM latency).
    if constexpr (R + 3 < RIN) {
        c.ex[R % 3] = c.Xp[(R + 3) * W4];
        c.ey[R % 3] = c.Yp[(R + 3) * W4];
    }
    // Refill: leave row R-6 for iteration R+1 (depth-1; L2 re-read ~250cy).
    if constexpr (R >= 6 && R <= 14) {
        c.lx = c.Xp[(R - 6) * W4];
        c.ly = c.Yp[(R - 6) * W4];
    }

    // Vertical slide (+ entering, - leaving; leaving is zeros for R <= 6).
    c.sx.x += xn.x - xo.x; c.sx.y += xn.y - xo.y;
    c.sx.z += xn.z - xo.z; c.sx.w += xn.w - xo.w;
    c.sy.x += yn.x - yo.x; c.sy.y += yn.y - yo.y;
    c.sy.z += yn.z - yo.z; c.sy.w += yn.w - yo.w;
    c.sxy.x = fmaf(xn.x, yn.x, fmaf(-xo.x, yo.x, c.sxy.x));
    c.sxy.y = fmaf(xn.y, yn.y, fmaf(-xo.y, yo.y, c.sxy.y));
    c.sxy.z = fmaf(xn.z, yn.z, fmaf(-xo.z, yo.z, c.sxy.z));
    c.sxy.w = fmaf(xn.w, yn.w, fmaf(-xo.w, yo.w, c.sxy.w));
    c.spp.x = fmaf(xn.x, xn.x, fmaf(yn.x, yn.x, fmaf(-xo.x, xo.x, fmaf(-yo.x, yo.x, c.spp.x))));
    c.spp.y = fmaf(xn.y, xn.y, fmaf(yn.y, yn.y, fmaf(-xo.y, xo.y, fmaf(-yo.y, yo.y, c.spp.y))));
    c.spp.z = fmaf(xn.z, xn.z, fmaf(yn.z, yn.z, fmaf(-xo.z, xo.z, fmaf(-yo.z, yo.z, c.spp.z))));
    c.spp.w = fmaf(xn.w, xn.w, fmaf(yn.w, yn.w, fmaf(-xo.w, xo.w, fmaf(-yo.w, yo.w, c.spp.w))));

    if constexpr (R >= 6) {
        float wx[4], wy[4], wpp[4], wxy[4];
        hwin4(c.sx,  wx);
        hwin4(c.sy,  wy);
        hwin4(c.spp, wpp);
        hwin4(c.sxy, wxy);
        #pragma unroll
        for (int s = 0; s < 4; ++s) {
            const float P  = wx[s] * wy[s];
            const float Qs = fmaf(wy[s], wy[s], wx[s] * wx[s]);
            const float A1 = fmaf(K2A, P, CC1);
            const float B1 = fmaf(KAA, Qs, CC1);
            const float A2 = fmaf(KT1, wxy[s], fmaf(KT2, P, CC2));
            const float B2 = fmaf(KT3, wpp[s], fmaf(KT4, Qs, CC2));
            const float S  = (A1 * A2) * __builtin_amdgcn_rcpf(B1 * B2);
            lsum = fmaf(S, (s < 2) ? m01 : m23, lsum);  // branchless col mask
        }
    }
    if constexpr (R + 1 < RIN) step<R + 1>(c, m01, m23, lsum);
}

__global__ __launch_bounds__(256) void ssim_band_kernel(
    const float* __restrict__ X, const float* __restrict__ Y,
    float* __restrict__ partial)
{
    const int lane = threadIdx.x & 63;          // owns cols 4*lane..4*lane+3
    const int wid  = blockIdx.x * WPB + (threadIdx.x >> 6);  // 0..6399
    const int img  = wid / NBANDS;              // 0..255
    const int band = wid % NBANDS;              // 0..24
    const int r0 = band * BAND;

    Ctx c;
    c.Xp = (const float4*)X + ((size_t)img * H + r0) * W4 + lane;
    c.Yp = (const float4*)Y + ((size_t)img * H + r0) * W4 + lane;
    c.sx = f4zero(); c.sy = f4zero(); c.sxy = f4zero(); c.spp = f4zero();
    // Preload enter pipeline: rows 0,1,2.
    c.ex[0] = c.Xp[0];      c.ey[0] = c.Yp[0];
    c.ex[1] = c.Xp[W4];     c.ey[1] = c.Yp[W4];
    c.ex[2] = c.Xp[2 * W4]; c.ey[2] = c.Yp[2 * W4];
    c.lx = f4zero(); c.ly = f4zero();

    // Column-validity masks (output cols 0..249):
    //   cols 4L+{0,1} valid iff lane <= 62; cols 4L+{2,3} valid iff lane <= 61.
    const float m01 = (lane <= 62) ? 1.0f : 0.0f;
    const float m23 = (lane <= 61) ? 1.0f : 0.0f;

    float lsum = 0.0f;
    step<0>(c, m01, m23, lsum);

    // Wave reduction -> one partial per wave.
    #pragma unroll
    for (int off = 32; off > 0; off >>= 1)
        lsum += __shfl_down(lsum, off, 64);
    if (lane == 0) partial[wid] = lsum;
}

__global__ __launch_bounds__(256) void ssim_reduce_kernel(
    const float* __restrict__ partial, float* __restrict__ out)
{
    const int tid = threadIdx.x;
    double acc = 0.0;
    for (int i = tid; i < NBLK; i += 256)
        acc += (double)partial[i];
    #pragma unroll
    for (int off = 32; off > 0; off >>= 1)
        acc += __shfl_down(acc, off, 64);
    __shared__ double wsumd[4];
    if ((tid & 63) == 0) wsumd[tid >> 6] = acc;
    __syncthreads();
    if (tid == 0) {
        double total = wsumd[0] + wsumd[1] + wsumd[2] + wsumd[3];
        float loss = (float)(1.0 - total / 16000000.0);
        out[0] = loss; out[1] = loss; out[2] = loss; out[3] = loss;
    }
}

extern "C" void kernel_launch(void* const* d_in, const int* in_sizes, int n_in,
                              void* d_out, int out_size, void* d_ws, size_t ws_size,
                              hipStream_t stream) {
    const float* X = (const float*)d_in[0];
    const float* Y = (const float*)d_in[1];
    // d_in[2] is the uniform 7x7 filter (1/49 everywhere) — constant-folded.
    float* out = (float*)d_out;
    float* partial = (float*)d_ws;   // 6400 floats = 25.6 KB

    hipLaunchKernelGGL(ssim_band_kernel, dim3(NBLOCKS), dim3(256), 0, stream,
                       X, Y, partial);
    hipLaunchKernelGGL(ssim_reduce_kernel, dim3(1), dim3(256), 0, stream,
                       partial, out);
}